// Round 1
// baseline (12253.522 us; speedup 1.0000x reference)
//
#include <hip/hip_runtime.h>

#define N_PTS 65536
#define DIM   1024
#define NCLS  256
#define NITER 25

// ---------------- argmax(logits) -> init labels (first-max tie-break) ---------
__global__ void k_argmax(const float* __restrict__ logits, int* __restrict__ labels) {
    int row  = blockIdx.x * 4 + (threadIdx.x >> 6);
    int lane = threadIdx.x & 63;
    float4 v = reinterpret_cast<const float4*>(logits + (size_t)row * NCLS)[lane];
    float bv = v.x; int bi = lane * 4;
    if (v.y > bv) { bv = v.y; bi = lane * 4 + 1; }
    if (v.z > bv) { bv = v.z; bi = lane * 4 + 2; }
    if (v.w > bv) { bv = v.w; bi = lane * 4 + 3; }
    #pragma unroll
    for (int off = 32; off >= 1; off >>= 1) {
        float ov = __shfl_down(bv, off, 64);
        int   oi = __shfl_down(bi, off, 64);
        if (ov > bv || (ov == bv && oi < bi)) { bv = ov; bi = oi; }
    }
    if (lane == 0) labels[row] = bi;
}

// ---------------- label histogram (int atomics -> deterministic) --------------
__global__ void k_hist(const int* __restrict__ labels, int* __restrict__ counts) {
    __shared__ int h[NCLS];
    h[threadIdx.x] = 0;
    __syncthreads();
    for (int i = blockIdx.x * blockDim.x + threadIdx.x; i < N_PTS;
         i += gridDim.x * blockDim.x)
        atomicAdd(&h[labels[i]], 1);
    __syncthreads();
    int v = h[threadIdx.x];
    if (v) atomicAdd(&counts[threadIdx.x], v);
}

// ---------------- segment-sum accumulate (fixed-point, deterministic) ---------
// grid: (32 dim-slices of 32 dims, 16 point-chunks of 4096). block = 512.
// LDS: 256 classes x 32 dims x u64 = 64 KB. Values scaled by 2^24.
__global__ __launch_bounds__(512) void k_accum(const float* __restrict__ feat,
                                               const int* __restrict__ labels,
                                               float* __restrict__ partials) {
    __shared__ unsigned long long s[NCLS * 32];
    int tid = threadIdx.x;
    for (int i = tid; i < NCLS * 32; i += 512) s[i] = 0ull;
    __syncthreads();
    int slice = blockIdx.x;            // dims slice*32 .. +31
    int chunk = blockIdx.y;            // points chunk*4096 .. +4095
    int w = tid >> 6, l = tid & 63;
    int sub = l >> 3;                  // point-within-wave 0..7
    int dq  = l & 7;                   // dim quad 0..7
    const size_t dbase = (size_t)slice * 32 + dq * 4;
    for (int step = 0; step < 64; ++step) {
        int p = chunk * 4096 + step * 64 + w * 8 + sub;
        int c = labels[p];
        float4 f = *reinterpret_cast<const float4*>(feat + (size_t)p * DIM + dbase);
        unsigned long long* dst = &s[c * 32 + dq * 4];
        atomicAdd(dst + 0, (unsigned long long)__double2ll_rn((double)f.x * 16777216.0));
        atomicAdd(dst + 1, (unsigned long long)__double2ll_rn((double)f.y * 16777216.0));
        atomicAdd(dst + 2, (unsigned long long)__double2ll_rn((double)f.z * 16777216.0));
        atomicAdd(dst + 3, (unsigned long long)__double2ll_rn((double)f.w * 16777216.0));
    }
    __syncthreads();
    float* out = partials + (size_t)chunk * NCLS * DIM;
    for (int i = tid; i < NCLS * 32; i += 512) {
        int c = i >> 5, d = i & 31;
        out[(size_t)c * DIM + slice * 32 + d] =
            (float)((double)(long long)s[i] * (1.0 / 16777216.0));
    }
}

// ---------------- reduce chunks, divide by counts, keep prev if empty ---------
__global__ void k_finalize(const float* __restrict__ partials,
                           const int* __restrict__ counts,
                           float* __restrict__ centroids) {
    int idx = blockIdx.x * blockDim.x + threadIdx.x;   // 65536 float4 cells
    int c = idx >> 8;
    size_t off = (size_t)idx * 4;
    float4 sum = make_float4(0.f, 0.f, 0.f, 0.f);
    for (int ch = 0; ch < 16; ++ch) {
        float4 p = *reinterpret_cast<const float4*>(partials + (size_t)ch * NCLS * DIM + off);
        sum.x += p.x; sum.y += p.y; sum.z += p.z; sum.w += p.w;
    }
    int cnt = counts[c];
    float4 outv;
    if (cnt > 0) {
        float fc = (float)cnt;
        outv = make_float4(sum.x / fc, sum.y / fc, sum.z / fc, sum.w / fc);
    } else {
        outv = *reinterpret_cast<const float4*>(centroids + off);
    }
    *reinterpret_cast<float4*>(centroids + off) = outv;
}

// ---------------- centroid squared norms ---------------------------------------
__global__ void k_norms(const float* __restrict__ centroids, float* __restrict__ norms) {
    int c = blockIdx.x;
    int t = threadIdx.x;                      // 256 threads, float4 each
    float4 v = reinterpret_cast<const float4*>(centroids + (size_t)c * DIM)[t];
    float s = v.x * v.x + v.y * v.y + v.z * v.z + v.w * v.w;
    __shared__ float red[4];
    #pragma unroll
    for (int off = 32; off >= 1; off >>= 1) s += __shfl_down(s, off, 64);
    if ((t & 63) == 0) red[t >> 6] = s;
    __syncthreads();
    if (t == 0) norms[c] = red[0] + red[1] + red[2] + red[3];
}

// ---------------- assign: fused fp32 GEMM (64pts x 256cls) + argmin ------------
#define ASG_KC 32
__global__ __launch_bounds__(256) void k_assign(const float* __restrict__ feat,
                                                const float* __restrict__ cent,
                                                const float* __restrict__ norms,
                                                int* __restrict__ labels) {
    __shared__ __align__(16) float Xs[ASG_KC][64];    // 8 KB  [k][point]
    __shared__ __align__(16) float Ms[ASG_KC][NCLS];  // 32 KB [k][class]
    __shared__ unsigned long long best[64];
    int tid = threadIdx.x;
    int p0 = blockIdx.x * 64;
    float acc[8][8];
    #pragma unroll
    for (int i = 0; i < 8; ++i)
        #pragma unroll
        for (int j = 0; j < 8; ++j) acc[i][j] = 0.f;

    int l = tid & 63, w = tid >> 6;
    int xp = w * 16 + (l >> 2);           // point 0..63 (4 lanes/row -> coalesced)
    int xk = (l & 3) * 4;                 // k sub-offset
    const float* xrow = feat + (size_t)(p0 + xp) * DIM;
    int mk    = (tid & 3) * 4;
    int cbase = tid >> 2;                 // 0..63

    for (int k0 = 0; k0 < DIM; k0 += ASG_KC) {
        __syncthreads();
        float4 a = *reinterpret_cast<const float4*>(xrow + k0 + xk);
        float4 b = *reinterpret_cast<const float4*>(xrow + k0 + 16 + xk);
        Xs[xk + 0][xp] = a.x; Xs[xk + 1][xp] = a.y;
        Xs[xk + 2][xp] = a.z; Xs[xk + 3][xp] = a.w;
        Xs[16 + xk + 0][xp] = b.x; Xs[16 + xk + 1][xp] = b.y;
        Xs[16 + xk + 2][xp] = b.z; Xs[16 + xk + 3][xp] = b.w;
        #pragma unroll
        for (int q = 0; q < 4; ++q) {
            int c = q * 64 + cbase;
            const float* mrow = cent + (size_t)c * DIM + k0;
            float4 ma = *reinterpret_cast<const float4*>(mrow + mk);
            float4 mb = *reinterpret_cast<const float4*>(mrow + 16 + mk);
            Ms[mk + 0][c] = ma.x; Ms[mk + 1][c] = ma.y;
            Ms[mk + 2][c] = ma.z; Ms[mk + 3][c] = ma.w;
            Ms[16 + mk + 0][c] = mb.x; Ms[16 + mk + 1][c] = mb.y;
            Ms[16 + mk + 2][c] = mb.z; Ms[16 + mk + 3][c] = mb.w;
        }
        __syncthreads();
        int pb = (tid & 7) * 8, cb = (tid >> 3) * 8;
        #pragma unroll
        for (int k = 0; k < ASG_KC; ++k) {
            float x[8], m[8];
            *reinterpret_cast<float4*>(&x[0]) = *reinterpret_cast<const float4*>(&Xs[k][pb]);
            *reinterpret_cast<float4*>(&x[4]) = *reinterpret_cast<const float4*>(&Xs[k][pb + 4]);
            *reinterpret_cast<float4*>(&m[0]) = *reinterpret_cast<const float4*>(&Ms[k][cb]);
            *reinterpret_cast<float4*>(&m[4]) = *reinterpret_cast<const float4*>(&Ms[k][cb + 4]);
            #pragma unroll
            for (int i = 0; i < 8; ++i)
                #pragma unroll
                for (int j = 0; j < 8; ++j)
                    acc[i][j] = fmaf(x[i], m[j], acc[i][j]);
        }
    }

    if (tid < 64) best[tid] = ~0ull;
    __syncthreads();
    int pb = (tid & 7) * 8, cb = (tid >> 3) * 8;
    float nrm[8];
    #pragma unroll
    for (int j = 0; j < 8; ++j) nrm[j] = norms[cb + j];
    #pragma unroll
    for (int i = 0; i < 8; ++i) {
        unsigned long long key = ~0ull;
        #pragma unroll
        for (int j = 0; j < 8; ++j) {
            float s = nrm[j] - 2.0f * acc[i][j];   // == -2*dot + ||mu||^2
            unsigned int u = __float_as_uint(s);
            u = (u & 0x80000000u) ? ~u : (u | 0x80000000u);  // order-preserving map
            unsigned long long kk = ((unsigned long long)u << 32) | (unsigned)(cb + j);
            key = (kk < key) ? kk : key;           // first-min tie-break via low idx
        }
        atomicMin(&best[pb + i], key);
    }
    __syncthreads();
    if (tid < 64) labels[p0 + tid] = (int)(best[tid] & 0xFFFFFFFFull);
}

// ---------------- driver -------------------------------------------------------
extern "C" void kernel_launch(void* const* d_in, const int* in_sizes, int n_in,
                              void* d_out, int out_size, void* d_ws, size_t ws_size,
                              hipStream_t stream) {
    const float* feat   = (const float*)d_in[0];
    const float* logits = (const float*)d_in[1];
    int* out_labels = (int*)d_out;

    char* ws = (char*)d_ws;
    float* centroids = (float*)ws;                          // 1 MB
    float* partials  = (float*)(ws + (1u << 20));           // 16 MB (16 chunks)
    float* norms     = (float*)(ws + (17u << 20));          // 1 KB
    int*   counts    = (int*)  (ws + (17u << 20) + 4096);   // 1 KB
    int*   labels    = (int*)  (ws + (17u << 20) + 8192);   // 256 KB

    // ---- init: labels from argmax(logits); centroids from label centers (prev=0)
    k_argmax<<<N_PTS / 4, 256, 0, stream>>>(logits, labels);
    hipMemsetAsync(centroids, 0, (size_t)NCLS * DIM * sizeof(float), stream);
    hipMemsetAsync(counts, 0, NCLS * sizeof(int), stream);
    k_hist<<<64, 256, 0, stream>>>(labels, counts);
    k_accum<<<dim3(32, 16), 512, 0, stream>>>(feat, labels, partials);
    k_finalize<<<256, 256, 0, stream>>>(partials, counts, centroids);

    // ---- 25 Lloyd iterations
    for (int it = 0; it < NITER; ++it) {
        k_norms<<<NCLS, 256, 0, stream>>>(centroids, norms);
        k_assign<<<N_PTS / 64, 256, 0, stream>>>(feat, centroids, norms, labels);
        hipMemsetAsync(counts, 0, NCLS * sizeof(int), stream);
        k_hist<<<64, 256, 0, stream>>>(labels, counts);
        k_accum<<<dim3(32, 16), 512, 0, stream>>>(feat, labels, partials);
        k_finalize<<<256, 256, 0, stream>>>(partials, counts, centroids);
    }

    // ---- final assignment -> output labels (int32)
    k_norms<<<NCLS, 256, 0, stream>>>(centroids, norms);
    k_assign<<<N_PTS / 64, 256, 0, stream>>>(feat, centroids, norms, out_labels);
}

// Round 2
// 7327.765 us; speedup vs baseline: 1.6722x; 1.6722x over previous
//
#include <hip/hip_runtime.h>

#define N_PTS 65536
#define DIM   1024
#define NCLS  256
#define NITER 25

typedef __attribute__((ext_vector_type(8)))  short short8;
typedef __attribute__((ext_vector_type(16))) float f32x16;

// ---- RNE float -> bf16 split helper ------------------------------------------
__device__ __forceinline__ unsigned short bf_split(float x, float& rem) {
    unsigned u = __float_as_uint(x);
    unsigned b = (u + 0x7fffu + ((u >> 16) & 1u)) & 0xffff0000u;
    rem = x - __uint_as_float(b);
    return (unsigned short)(b >> 16);
}
__device__ __forceinline__ unsigned short bf_rne(float x) {
    unsigned u = __float_as_uint(x);
    return (unsigned short)((u + 0x7fffu + ((u >> 16) & 1u)) >> 16);
}

// ---- async global->LDS 16B DMA (lds base must be wave-uniform) ---------------
__device__ __forceinline__ void gload_lds16(const void* g, void* l) {
    __builtin_amdgcn_global_load_lds(
        (const __attribute__((address_space(1))) unsigned int*)g,
        (__attribute__((address_space(3))) unsigned int*)l, 16, 0, 0);
}

// ---------------- argmax(logits) -> init labels (first-max tie-break) ---------
__global__ void k_argmax(const float* __restrict__ logits, int* __restrict__ labels) {
    int row  = blockIdx.x * 4 + (threadIdx.x >> 6);
    int lane = threadIdx.x & 63;
    float4 v = reinterpret_cast<const float4*>(logits + (size_t)row * NCLS)[lane];
    float bv = v.x; int bi = lane * 4;
    if (v.y > bv) { bv = v.y; bi = lane * 4 + 1; }
    if (v.z > bv) { bv = v.z; bi = lane * 4 + 2; }
    if (v.w > bv) { bv = v.w; bi = lane * 4 + 3; }
    #pragma unroll
    for (int off = 32; off >= 1; off >>= 1) {
        float ov = __shfl_down(bv, off, 64);
        int   oi = __shfl_down(bi, off, 64);
        if (ov > bv || (ov == bv && oi < bi)) { bv = ov; bi = oi; }
    }
    if (lane == 0) labels[row] = bi;
}

// ---------------- label histogram ---------------------------------------------
__global__ void k_hist(const int* __restrict__ labels, int* __restrict__ counts) {
    __shared__ int h[NCLS];
    h[threadIdx.x] = 0;
    __syncthreads();
    for (int i = blockIdx.x * blockDim.x + threadIdx.x; i < N_PTS;
         i += gridDim.x * blockDim.x)
        atomicAdd(&h[labels[i]], 1);
    __syncthreads();
    int v = h[threadIdx.x];
    if (v) atomicAdd(&counts[threadIdx.x], v);
}

// ---------------- segment-sum accumulate (fixed-point, deterministic) ---------
// grid (32 dim-slices, 8 point-chunks of 8192), block 512, LDS 64 KB
__global__ __launch_bounds__(512) void k_accum(const float* __restrict__ feat,
                                               const int* __restrict__ labels,
                                               float* __restrict__ partials) {
    __shared__ unsigned long long s[NCLS * 32];
    int tid = threadIdx.x;
    for (int i = tid; i < NCLS * 32; i += 512) s[i] = 0ull;
    __syncthreads();
    int slice = blockIdx.x;
    int chunk = blockIdx.y;
    int w = tid >> 6, l = tid & 63;
    int sub = l >> 3;
    int dq  = l & 7;
    const size_t dbase = (size_t)slice * 32 + dq * 4;
    for (int step = 0; step < 128; ++step) {
        int p = chunk * 8192 + step * 64 + w * 8 + sub;
        int c = labels[p];
        float4 f = *reinterpret_cast<const float4*>(feat + (size_t)p * DIM + dbase);
        unsigned long long* dst = &s[c * 32 + dq * 4];
        atomicAdd(dst + 0, (unsigned long long)__double2ll_rn((double)f.x * 16777216.0));
        atomicAdd(dst + 1, (unsigned long long)__double2ll_rn((double)f.y * 16777216.0));
        atomicAdd(dst + 2, (unsigned long long)__double2ll_rn((double)f.z * 16777216.0));
        atomicAdd(dst + 3, (unsigned long long)__double2ll_rn((double)f.w * 16777216.0));
    }
    __syncthreads();
    float* out = partials + (size_t)chunk * NCLS * DIM;
    for (int i = tid; i < NCLS * 32; i += 512) {
        int c = i >> 5, d = i & 31;
        out[(size_t)c * DIM + slice * 32 + d] =
            (float)((double)(long long)s[i] * (1.0 / 16777216.0));
    }
}

// ---------------- reduce chunks, divide, keep prev if empty -------------------
__global__ void k_finalize(const float* __restrict__ partials,
                           const int* __restrict__ counts,
                           float* __restrict__ centroids) {
    int idx = blockIdx.x * blockDim.x + threadIdx.x;   // 65536 float4 cells
    int c = idx >> 8;
    size_t off = (size_t)idx * 4;
    float4 sum = make_float4(0.f, 0.f, 0.f, 0.f);
    for (int ch = 0; ch < 8; ++ch) {
        float4 p = *reinterpret_cast<const float4*>(partials + (size_t)ch * NCLS * DIM + off);
        sum.x += p.x; sum.y += p.y; sum.z += p.z; sum.w += p.w;
    }
    int cnt = counts[c];
    float4 outv;
    if (cnt > 0) {
        float fc = (float)cnt;
        outv = make_float4(sum.x / fc, sum.y / fc, sum.z / fc, sum.w / fc);
    } else {
        outv = *reinterpret_cast<const float4*>(centroids + off);
    }
    *reinterpret_cast<float4*>(centroids + off) = outv;
}

// ---------------- centroid squared norms --------------------------------------
__global__ void k_norms(const float* __restrict__ centroids, float* __restrict__ norms) {
    int c = blockIdx.x;
    int t = threadIdx.x;
    float4 v = reinterpret_cast<const float4*>(centroids + (size_t)c * DIM)[t];
    float s = v.x * v.x + v.y * v.y + v.z * v.z + v.w * v.w;
    __shared__ float red[4];
    #pragma unroll
    for (int off = 32; off >= 1; off >>= 1) s += __shfl_down(s, off, 64);
    if ((t & 63) == 0) red[t >> 6] = s;
    __syncthreads();
    if (t == 0) norms[c] = red[0] + red[1] + red[2] + red[3];
}

// ---------------- centroid bf16x3 split, MFMA-fragment-ordered ----------------
// Bs layout (ushort): [kc 32][plane 3][ntile 8][kh 2][lane 64][j 8]
// element (n,k,plane): kc=k>>5, kh=(k>>4)&1, jg=(k>>3)&1, j=k&7,
//                      nt=n>>5, lane=(n&31)+32*jg
__global__ void k_splitB(const float* __restrict__ cent, unsigned short* __restrict__ Bs) {
    int lin = blockIdx.x * 256 + threadIdx.x;   // 32768 threads
    int n = lin & 255, kg = lin >> 8;           // kg: 8-dim group 0..127
    int k = kg * 8;
    int kc = kg >> 2, kh = (kg >> 1) & 1, jg = kg & 1;
    int nt = n >> 5, lane = (n & 31) + 32 * jg;
    const float* src = cent + (size_t)n * DIM + k;
    unsigned short hi[8], mi[8], lo[8];
    #pragma unroll
    for (int j = 0; j < 8; ++j) {
        float r1, r2;
        hi[j] = bf_split(src[j], r1);
        mi[j] = bf_split(r1, r2);
        lo[j] = bf_rne(r2);
    }
    #pragma unroll
    for (int p = 0; p < 3; ++p) {
        size_t base = ((((size_t)kc * 3 + p) * 8 + nt) * 2 + kh) * 512 + (size_t)lane * 8;
        const unsigned short* srcp = (p == 0) ? hi : (p == 1) ? mi : lo;
        uint4 pack = *reinterpret_cast<const uint4*>(srcp);
        *reinterpret_cast<uint4*>(Bs + base) = pack;
    }
}

// ---------------- assign: bf16x3 MFMA GEMM + fused argmin ----------------------
// block 256 (4 waves), tile M=128 (32/wave) x N=128 (blockIdx.y half)
// A-fragments built in-register from the lane's own global floats (no LDS).
// B staged via global_load_lds into fragment-ordered LDS (24 KB).
__global__ __launch_bounds__(256, 3) void k_assign(
        const float* __restrict__ feat, const unsigned short* __restrict__ Bs,
        const float* __restrict__ norms, unsigned long long* __restrict__ part) {
    __shared__ __align__(16) unsigned short Bl[24 * 512];   // [q][ntl][kh][lane][8]
    int tid = threadIdx.x, w = tid >> 6, l = tid & 63;
    int cn = l & 31, jg = l >> 5;
    int p0 = blockIdx.x * 128;
    int nh = blockIdx.y;
    int n0 = nh * 128;

    f32x16 acc[4];
    #pragma unroll
    for (int t = 0; t < 4; ++t)
        #pragma unroll
        for (int i = 0; i < 16; ++i) acc[t][i] = 0.f;

    const float* arow = feat + (size_t)(p0 + w * 32 + cn) * DIM + jg * 8;

    for (int kc = 0; kc < 32; ++kc) {
        int k0 = kc * 32;
        // A global loads early (overlap prior compute / barrier)
        float4 g0 = *reinterpret_cast<const float4*>(arow + k0);
        float4 g1 = *reinterpret_cast<const float4*>(arow + k0 + 4);
        float4 g2 = *reinterpret_cast<const float4*>(arow + k0 + 16);
        float4 g3 = *reinterpret_cast<const float4*>(arow + k0 + 20);
        __syncthreads();   // prior chunk's B reads complete before overwrite
        // B DMA: this wave's 6 of 24 segments (1024 B each)
        #pragma unroll
        for (int i = 0; i < 6; ++i) {
            int s = w * 6 + i;                     // s = ((q*4+ntl)*2+kh)
            int kh = s & 1, ntl = (s >> 1) & 3, q = s >> 3;
            int ntg = nh * 4 + ntl;
            const unsigned short* g =
                Bs + ((((size_t)kc * 3 + q) * 8 + ntg) * 2 + kh) * 512 + (size_t)l * 8;
            gload_lds16(g, &Bl[s * 512]);
        }
        // A split in-register -> fragments
        float xs[16] = {g0.x, g0.y, g0.z, g0.w, g1.x, g1.y, g1.z, g1.w,
                        g2.x, g2.y, g2.z, g2.w, g3.x, g3.y, g3.z, g3.w};
        union { short8 v; unsigned short u[8]; } af[2][3];
        #pragma unroll
        for (int kh = 0; kh < 2; ++kh)
            #pragma unroll
            for (int j = 0; j < 8; ++j) {
                float r1, r2;
                af[kh][0].u[j] = bf_split(xs[kh * 8 + j], r1);
                af[kh][1].u[j] = bf_split(r1, r2);
                af[kh][2].u[j] = bf_rne(r2);
            }
        __syncthreads();   // drains vmcnt: B DMA visible
        // 6 split-product pairings: (h,h)(m,h)(l,h)(h,m)(m,m)(h,l)
        #pragma unroll
        for (int q = 0; q < 3; ++q)
            #pragma unroll
            for (int ntl = 0; ntl < 4; ++ntl)
                #pragma unroll
                for (int kh = 0; kh < 2; ++kh) {
                    int s = (q * 4 + ntl) * 2 + kh;
                    short8 bf = *reinterpret_cast<const short8*>(&Bl[s * 512 + l * 8]);
                    acc[ntl] = __builtin_amdgcn_mfma_f32_32x32x16_bf16(
                        af[kh][0].v, bf, acc[ntl], 0, 0, 0);
                    if (q < 2)
                        acc[ntl] = __builtin_amdgcn_mfma_f32_32x32x16_bf16(
                            af[kh][1].v, bf, acc[ntl], 0, 0, 0);
                    if (q == 0)
                        acc[ntl] = __builtin_amdgcn_mfma_f32_32x32x16_bf16(
                            af[kh][2].v, bf, acc[ntl], 0, 0, 0);
                }
    }

    // epilogue: scores = ||mu||^2 - 2*dot ; argmin with first-index tie-break
    float nrm[4];
    #pragma unroll
    for (int ntl = 0; ntl < 4; ++ntl) nrm[ntl] = norms[n0 + ntl * 32 + cn];
    #pragma unroll
    for (int r = 0; r < 16; ++r) {
        unsigned long long key = ~0ull;
        #pragma unroll
        for (int ntl = 0; ntl < 4; ++ntl) {
            float s = nrm[ntl] - 2.0f * acc[ntl][r];
            unsigned u = __float_as_uint(s);
            u = (u & 0x80000000u) ? ~u : (u | 0x80000000u);
            unsigned long long kk =
                ((unsigned long long)u << 32) | (unsigned)(n0 + ntl * 32 + cn);
            key = (kk < key) ? kk : key;
        }
        #pragma unroll
        for (int off = 16; off >= 1; off >>= 1) {
            unsigned long long ok = __shfl_xor(key, off, 64);
            key = (ok < key) ? ok : key;
        }
        if (cn == 0) {
            int m = p0 + w * 32 + (r & 3) + 8 * (r >> 2) + 4 * jg;
            part[(size_t)nh * N_PTS + m] = key;
        }
    }
}

// ---------------- combine the two N-halves, extract labels --------------------
__global__ void k_combine(const unsigned long long* __restrict__ part,
                          int* __restrict__ labels) {
    int i = blockIdx.x * blockDim.x + threadIdx.x;
    unsigned long long a = part[i], b = part[N_PTS + i];
    unsigned long long k = (b < a) ? b : a;
    labels[i] = (int)(k & 0xffffffffull);
}

// ---------------- driver -------------------------------------------------------
extern "C" void kernel_launch(void* const* d_in, const int* in_sizes, int n_in,
                              void* d_out, int out_size, void* d_ws, size_t ws_size,
                              hipStream_t stream) {
    const float* feat   = (const float*)d_in[0];
    const float* logits = (const float*)d_in[1];
    int* out_labels = (int*)d_out;

    char* ws = (char*)d_ws;
    float* centroids            = (float*)ws;                        // 1 MB
    float* partials             = (float*)(ws + 0x100000);           // 8 MB
    float* norms                = (float*)(ws + 0x900000);           // 1 KB
    int*   counts               = (int*)  (ws + 0x901000);           // 1 KB
    int*   labels               = (int*)  (ws + 0x902000);           // 256 KB
    unsigned short* Bs          = (unsigned short*)(ws + 0x950000);  // 1.5 MB
    unsigned long long* part    = (unsigned long long*)(ws + 0xAD0000); // 1 MB

    // ---- init: labels from argmax(logits); centroids from label centers
    k_argmax<<<N_PTS / 4, 256, 0, stream>>>(logits, labels);
    hipMemsetAsync(centroids, 0, (size_t)NCLS * DIM * sizeof(float), stream);
    hipMemsetAsync(counts, 0, NCLS * sizeof(int), stream);
    k_hist<<<64, 256, 0, stream>>>(labels, counts);
    k_accum<<<dim3(32, 8), 512, 0, stream>>>(feat, labels, partials);
    k_finalize<<<256, 256, 0, stream>>>(partials, counts, centroids);

    // ---- 25 Lloyd iterations
    for (int it = 0; it < NITER; ++it) {
        k_norms<<<NCLS, 256, 0, stream>>>(centroids, norms);
        k_splitB<<<128, 256, 0, stream>>>(centroids, Bs);
        k_assign<<<dim3(N_PTS / 128, 2), 256, 0, stream>>>(feat, Bs, norms, part);
        k_combine<<<N_PTS / 256, 256, 0, stream>>>(part, labels);
        hipMemsetAsync(counts, 0, NCLS * sizeof(int), stream);
        k_hist<<<64, 256, 0, stream>>>(labels, counts);
        k_accum<<<dim3(32, 8), 512, 0, stream>>>(feat, labels, partials);
        k_finalize<<<256, 256, 0, stream>>>(partials, counts, centroids);
    }

    // ---- final assignment -> output labels (int32)
    k_norms<<<NCLS, 256, 0, stream>>>(centroids, norms);
    k_splitB<<<128, 256, 0, stream>>>(centroids, Bs);
    k_assign<<<dim3(N_PTS / 128, 2), 256, 0, stream>>>(feat, Bs, norms, part);
    k_combine<<<N_PTS / 256, 256, 0, stream>>>(part, out_labels);
}